// Round 7
// baseline (2156.050 us; speedup 1.0000x reference)
//
#include <hip/hip_runtime.h>
#include <stdint.h>
#include <math.h>

// Problem constants (from reference)
constexpr int kB = 8;      // clouds
constexpr int kP = 8192;   // points per cloud
constexpr int kF = 32;     // feature dim
constexpr int kM = 2048;   // centroids per cloud (P * 0.25)
constexpr int kK = 64;     // max neighbors
constexpr int kO = 128;    // output dim

typedef float v2f __attribute__((ext_vector_type(2)));
typedef _Float16 h8 __attribute__((ext_vector_type(8)));
typedef float f4v __attribute__((ext_vector_type(4)));
typedef unsigned long long u64x2 __attribute__((ext_vector_type(2)));

// Exact-f32 squared distance matching numpy: square elementwise, then
// sequential sum ((dx2+dy2)+dz2). contract(off) forbids fma fusion so this
// matches numpy bit-for-bit regardless of -ffp-contract=fast default.
__device__ __forceinline__ float dist2(float ax, float ay, float az,
                                       float bx, float by, float bz) {
#pragma clang fp contract(off)
    float dx = ax - bx, dy = ay - by, dz = az - bz;
    return (dx * dx + dy * dy) + dz * dz;
}

// Packed-f32 squared distance for TWO points in ONE asm block.
// Math is bit-identical to the scalar path: v_pk_add_f32 with neg modifier
// on src1 is an exact IEEE subtract; pk mul/add round identically to their
// scalar forms; sum order is (dx*dx + dy*dy) + dz*dz.
// r5 post-mortem: these exact instructions passed correctness on HW; the
// regression there came from 128 one-instr asm blocks (pair-alignment
// copies + scheduler fragmentation). One fused block per q keeps operands
// in persistent aligned pairs and gives the scheduler 16 coarse,
// reorderable, side-effect-free units whose internal 4-deep chain
// (~16 cyc) self-covers its own issue time.
__device__ __forceinline__ v2f pk_d2(v2f px, v2f py, v2f pz,
                                     v2f lx2, v2f ly2, v2f lz2) {
    v2f d2, t1, t2;
    asm("v_pk_add_f32 %0, %3, %6 neg_lo:[0,1] neg_hi:[0,1]\n\t"
        "v_pk_add_f32 %1, %4, %7 neg_lo:[0,1] neg_hi:[0,1]\n\t"
        "v_pk_add_f32 %2, %5, %8 neg_lo:[0,1] neg_hi:[0,1]\n\t"
        "v_pk_mul_f32 %0, %0, %0\n\t"
        "v_pk_mul_f32 %1, %1, %1\n\t"
        "v_pk_mul_f32 %2, %2, %2\n\t"
        "v_pk_add_f32 %0, %0, %1\n\t"
        "v_pk_add_f32 %0, %0, %2"
        : "=&v"(d2), "=&v"(t1), "=&v"(t2)
        : "v"(px), "v"(py), "v"(pz), "v"(lx2), "v"(ly2), "v"(lz2));
    return d2;
}

// One DPP step of a u64 (hi,lo) max-reduce. CTRL must be an immediate ->
// template parameter. bound_ctrl=true: invalid source lanes read 0, and
// (0,0) never wins because all real keys have klo = ~idx != 0.
// Compare as a single u64 '>' (lexicographic == the (hi>)||(hi==&&lo>)
// ladder): lets the compiler emit v_cmp_gt_u64 + 2 cndmask instead of
// 3 compares + SALU mask combines. Plain C++ — no asm (r1/r5 lesson).
template <int CTRL>
__device__ __forceinline__ void dpp_max_step(unsigned int& khi, unsigned int& klo) {
    unsigned int ohi = (unsigned int)__builtin_amdgcn_update_dpp(
        0, (int)khi, CTRL, 0xf, 0xf, true);
    unsigned int olo = (unsigned int)__builtin_amdgcn_update_dpp(
        0, (int)klo, CTRL, 0xf, 0xf, true);
    unsigned long long k = ((unsigned long long)khi << 32) | klo;
    unsigned long long o = ((unsigned long long)ohi << 32) | olo;
    bool take = o > k;
    khi = take ? ohi : khi;
    klo = take ? olo : klo;
}

// Zero the progress flags (d_ws is poisoned 0xAA before every launch).
__global__ void init_kernel(int* __restrict__ prog) {
    if (threadIdx.x < 128) prog[threadIdx.x] = 0;
}

// Role-union LDS. fps: big coord arrays (~100 KB). consumer: fp16 MFMA
// tiles + transposed fp16 weights (~121 KB). 1 block/CU either way.
union SharedU {
    struct {
        float sxp[kP], syp[kP], szp[kP];       // SoA cloud copy
        unsigned short widx[kM];               // winner index per iteration
        alignas(16) unsigned long long part[2][4];  // ping-pong wave partials
    } f;
    struct {
        _Float16 A0[256][72];                  // msg (cols 0..63), reused as h2
        _Float16 A1[256][72];                  // h1
        _Float16 Wt1[64][72];                  // W1^T [n][k], k>=35 zero
        _Float16 Wt2[64][72];                  // W2^T [n][k]
        _Float16 Wt3[128][72];                 // W3^T [n][k]
        float bias[256];                       // b1 | b2 | b3
        float red[4][4][128];                  // [centroid][quad][col]
        int   s_nb[4][kK];
        int   s_cnt[4];
    } c;
};

// ---------------------------------------------------------------------------
// Mega-kernel: producer/consumer overlap.
//  blocks 0..7    : FPS for cloud b (r6 structure; fused-block pk update —
//                   the single change this round).
//  blocks 8..4103 : 4 consecutive centroids of cloud b = i&7.
//                   Stage weights -> spin on prog[b] -> per-wave ball query
//                   -> per-wave gather -> per-wave fp16 MFMA MLP (fp32 acc)
//                   -> fused masked max -> cross-quad reduce -> feat_out.
// NOTE: __syncthreads() at EVERY consumer phase boundary. Wave-internal DS
// ordering is a HW property, but the compiler may hoist LDS loads (s_cnt is
// loop-invariant and never stored by this thread) above prior phases'
// stores — that hoist caused r13's garbage-index global OOB fault. Barriers
// are full compiler+HW fences; cost ~100cyc each vs ~15µs block.
// ---------------------------------------------------------------------------
__global__ __launch_bounds__(256, 1) void mega_kernel(
    const float* __restrict__ pos, const float* __restrict__ x,
    const float* __restrict__ W1, const float* __restrict__ b1,
    const float* __restrict__ W2, const float* __restrict__ b2,
    const float* __restrict__ W3, const float* __restrict__ b3,
    unsigned int* __restrict__ stage, int* __restrict__ prog,
    float* __restrict__ cent_out, float* __restrict__ feat_out,
    float* __restrict__ batch_out) {
    __shared__ SharedU sh;

    const int tid = threadIdx.x;
    const int wave = tid >> 6, lane = tid & 63;

    if (blockIdx.x < (unsigned)kB) {
        // ======================= FPS role ==================================
        const int b = blockIdx.x;
        const float* pb = pos + (size_t)b * kP * 3;

        v2f px2[16], py2[16], pz2[16], dd2[16];
#pragma unroll
        for (int q = 0; q < 32; ++q) {
            int i = tid + q * 256;
            float X = pb[i * 3 + 0];
            float Y = pb[i * 3 + 1];
            float Z = pb[i * 3 + 2];
            sh.f.sxp[i] = X; sh.f.syp[i] = Y; sh.f.szp[i] = Z;
            if (q & 1) { px2[q >> 1].y = X; py2[q >> 1].y = Y; pz2[q >> 1].y = Z; }
            else       { px2[q >> 1].x = X; py2[q >> 1].x = Y; pz2[q >> 1].x = Z; }
        }
#pragma unroll
        for (int q = 0; q < 16; ++q) dd2[q] = (v2f){INFINITY, INFINITY};

        if (tid == 0) sh.f.widx[0] = 0;
        __syncthreads();

        float lx = sh.f.sxp[0], ly = sh.f.syp[0], lz = sh.f.szp[0];
        if (tid == 0) {
            size_t o = (size_t)(b * kM) * 3;
            __hip_atomic_store(&stage[o + 0], __float_as_uint(lx),
                               __ATOMIC_RELAXED, __HIP_MEMORY_SCOPE_AGENT);
            __hip_atomic_store(&stage[o + 1], __float_as_uint(ly),
                               __ATOMIC_RELAXED, __HIP_MEMORY_SCOPE_AGENT);
            __hip_atomic_store(&stage[o + 2], __float_as_uint(lz),
                               __ATOMIC_RELAXED, __HIP_MEMORY_SCOPE_AGENT);
            __hip_atomic_store(&prog[b * 16], 1,
                               __ATOMIC_RELEASE, __HIP_MEMORY_SCOPE_AGENT);
        }

        for (int m = 1; m < kM; ++m) {
            v2f lxv = {lx, lx}, lyv = {ly, ly}, lzv = {lz, lz};
            // packed update: one fused 8-instr VOP3P block per q (exact),
            // scalar fminf outside the block.
#pragma unroll
            for (int q = 0; q < 16; ++q) {
                v2f d2 = pk_d2(px2[q], py2[q], pz2[q], lxv, lyv, lzv);
                dd2[q].x = fminf(dd2[q].x, d2.x);
                dd2[q].y = fminf(dd2[q].y, d2.y);
            }

            // Fused argmax tree over 32 slots: at every node the left child
            // covers strictly lower slots; right wins only on STRICT '>'.
            // => max value with lowest slot on ties == reference first-max
            // (global point index i = tid + slot*256 is slot-major per thread).
            float v0[16]; int s0[16];
#pragma unroll
            for (int q = 0; q < 16; ++q) {
                bool t = dd2[q].y > dd2[q].x;
                v0[q] = t ? dd2[q].y : dd2[q].x;
                s0[q] = t ? (2 * q + 1) : (2 * q);
            }
            float v1[8]; int s1[8];
#pragma unroll
            for (int q = 0; q < 8; ++q) {
                bool t = v0[2 * q + 1] > v0[2 * q];
                v1[q] = t ? v0[2 * q + 1] : v0[2 * q];
                s1[q] = t ? s0[2 * q + 1] : s0[2 * q];
            }
            float v2[4]; int s2[4];
#pragma unroll
            for (int q = 0; q < 4; ++q) {
                bool t = v1[2 * q + 1] > v1[2 * q];
                v2[q] = t ? v1[2 * q + 1] : v1[2 * q];
                s2[q] = t ? s1[2 * q + 1] : s1[2 * q];
            }
            float v3[2]; int s3[2];
#pragma unroll
            for (int q = 0; q < 2; ++q) {
                bool t = v2[2 * q + 1] > v2[2 * q];
                v3[q] = t ? v2[2 * q + 1] : v2[2 * q];
                s3[q] = t ? s2[2 * q + 1] : s2[2 * q];
            }
            bool tf = v3[1] > v3[0];
            float bv = tf ? v3[1] : v3[0];
            int bq = tf ? s3[1] : s3[0];

            unsigned int bidx = (unsigned int)(tid + bq * 256);
            unsigned int khi = __float_as_uint(bv);
            unsigned int klo = (unsigned int)(~bidx);

            dpp_max_step<0x111>(khi, klo);
            dpp_max_step<0x112>(khi, klo);
            dpp_max_step<0x114>(khi, klo);
            dpp_max_step<0x118>(khi, klo);
            dpp_max_step<0x142>(khi, klo);
            dpp_max_step<0x143>(khi, klo);
            if (lane == 63)
                sh.f.part[m & 1][wave] = ((unsigned long long)khi << 32) | klo;
            __syncthreads();

            // Pairwise combine of 4 wave partials (b128 loads, depth-2 tree).
            // Max is order-independent and keys unique -> same winner as the
            // serial scan.
            u64x2 pA = *(const u64x2*)&sh.f.part[m & 1][0];
            u64x2 pB = *(const u64x2*)&sh.f.part[m & 1][2];
            unsigned long long ka = pA.x > pA.y ? pA.x : pA.y;
            unsigned long long kb = pB.x > pB.y ? pB.x : pB.y;
            unsigned long long k  = ka > kb ? ka : kb;
            unsigned int wi = ~(unsigned int)k;
            lx = sh.f.sxp[wi]; ly = sh.f.syp[wi]; lz = sh.f.szp[wi];
            if (tid == 0) sh.f.widx[m] = (unsigned short)wi;

            if ((m & 31) == 31) {
                int m0 = m - 31;
                if (tid < 96) {
                    int mm = m0 + tid / 3;
                    int comp = tid % 3;
                    unsigned int w2 = (mm == m) ? wi
                                                : (unsigned int)sh.f.widx[mm];
                    float v = (comp == 0) ? sh.f.sxp[w2]
                            : (comp == 1) ? sh.f.syp[w2] : sh.f.szp[w2];
                    __hip_atomic_store(&stage[(size_t)(b * kM + mm) * 3 + comp],
                                       __float_as_uint(v),
                                       __ATOMIC_RELAXED, __HIP_MEMORY_SCOPE_AGENT);
                }
                __syncthreads();
                if (tid == 0)
                    __hip_atomic_store(&prog[b * 16], m + 1,
                                       __ATOMIC_RELEASE, __HIP_MEMORY_SCOPE_AGENT);
            }
        }
        __syncthreads();

#pragma unroll
        for (int q = 0; q < kM / 256; ++q) {
            int i = tid + q * 256;
            unsigned int wi = sh.f.widx[i];
            size_t o = (size_t)(b * kM + i) * 3;
            cent_out[o + 0] = sh.f.sxp[wi];
            cent_out[o + 1] = sh.f.syp[wi];
            cent_out[o + 2] = sh.f.szp[wi];
        }
        return;
    }

    // ======================= consumer role (G=4, MFMA) =====================
    const int i = (int)blockIdx.x - kB;
    const int b = i & 7;                 // cloud-rotated dispatch
    const int cl0 = (i >> 3) * 4;        // first of 4 centroids

    // --- stage weights/biases (independent of fps progress) ---
    for (int idx = tid; idx < 64 * 64; idx += 256) {
        int n = idx & 63, kk = idx >> 6;
        sh.c.Wt1[n][kk] = (_Float16)((kk < 35) ? W1[kk * 64 + n] : 0.0f);
        sh.c.Wt2[n][kk] = (_Float16)W2[kk * 64 + n];
    }
    for (int idx = tid; idx < 64 * 128; idx += 256) {
        int n = idx & 127, kk = idx >> 7;
        sh.c.Wt3[n][kk] = (_Float16)W3[kk * 128 + n];
    }
    sh.c.bias[tid] = (tid < 64) ? b1[tid] : (tid < 128) ? b2[tid - 64]
                                                        : b3[tid - 128];

    // --- wait until fps has published all 4 centroids ---
    if (tid == 0) {
        int p;
        while ((p = __hip_atomic_load(&prog[b * 16], __ATOMIC_ACQUIRE,
                                      __HIP_MEMORY_SCOPE_AGENT)) < cl0 + 4) {
            if (cl0 + 4 - p > 128) __builtin_amdgcn_s_sleep(64);
            else                   __builtin_amdgcn_s_sleep(8);
        }
    }
    __syncthreads();   // orders weight staging + spin vs everything below

    // --- ball query: wave w owns centroid cl0+w (fp32-exact) ---
    const int c = b * kM + cl0 + wave;
    float cx = __uint_as_float(__hip_atomic_load(&stage[(size_t)c * 3 + 0],
                   __ATOMIC_RELAXED, __HIP_MEMORY_SCOPE_AGENT));
    float cy = __uint_as_float(__hip_atomic_load(&stage[(size_t)c * 3 + 1],
                   __ATOMIC_RELAXED, __HIP_MEMORY_SCOPE_AGENT));
    float cz = __uint_as_float(__hip_atomic_load(&stage[(size_t)c * 3 + 2],
                   __ATOMIC_RELAXED, __HIP_MEMORY_SCOPE_AGENT));
    {
        const float R2 = (float)(0.2 * 0.2);
        const float* pb = pos + (size_t)b * kP * 3;
        int cnt = 0;
        for (int p0 = 0; p0 < kP && cnt < kK; p0 += 64) {
            int idx = p0 + lane;
            float X = pb[idx * 3 + 0], Y = pb[idx * 3 + 1], Z = pb[idx * 3 + 2];
            float d2 = dist2(X, Y, Z, cx, cy, cz);
            bool in = d2 <= R2;
            unsigned long long mask = __ballot(in);
            int rank = __popcll(mask & ((1ull << lane) - 1ull));
            if (in && cnt + rank < kK) sh.c.s_nb[wave][cnt + rank] = idx;
            cnt = min(cnt + (int)__popcll(mask), kK);
        }
        if (lane == 0) { sh.c.s_cnt[wave] = cnt; batch_out[c] = (float)b; }
    }
    __syncthreads();   // fence: s_nb/s_cnt stores -> reads (compiler+HW)
    const int cntw = sh.c.s_cnt[wave];

    // --- gather: thread = row tid = (wave,lane); msg cols 0..63 (35 used) ---
    {
        int k = lane;
        if (k < cntw) {
            int n = sh.c.s_nb[wave][k];
            const float4* xr4 = (const float4*)(x + ((size_t)b * kP + n) * kF);
#pragma unroll
            for (int t = 0; t < 4; ++t) {
                float4 a4 = xr4[2 * t], c4 = xr4[2 * t + 1];
                h8 o = {(_Float16)a4.x, (_Float16)a4.y, (_Float16)a4.z,
                        (_Float16)a4.w, (_Float16)c4.x, (_Float16)c4.y,
                        (_Float16)c4.z, (_Float16)c4.w};
                *(h8*)&sh.c.A0[tid][t * 8] = o;
            }
            float dx = pos[((size_t)b * kP + n) * 3 + 0] - cx;
            float dy = pos[((size_t)b * kP + n) * 3 + 1] - cy;
            float dz = pos[((size_t)b * kP + n) * 3 + 2] - cz;
            h8 o4 = {(_Float16)dx, (_Float16)dy, (_Float16)dz,
                     (_Float16)0.f, (_Float16)0.f, (_Float16)0.f,
                     (_Float16)0.f, (_Float16)0.f};
            *(h8*)&sh.c.A0[tid][32] = o4;
            h8 z = {};
            *(h8*)&sh.c.A0[tid][40] = z;
            *(h8*)&sh.c.A0[tid][48] = z;
            *(h8*)&sh.c.A0[tid][56] = z;
        } else {
            h8 z = {};
#pragma unroll
            for (int t = 0; t < 8; ++t) *(h8*)&sh.c.A0[tid][t * 8] = z;
        }
    }
    __syncthreads();   // fence: A0 stores -> MFMA A-fragment reads

    const int m16 = lane & 15, quad = lane >> 4;

    // --- layer 1: A0(msg) x Wt1 -> A1(h1), N=64, K=64 (fp16 MFMA, f32 acc)
    {
        h8 bf[4][2];
#pragma unroll
        for (int nt = 0; nt < 4; ++nt)
#pragma unroll
            for (int kc = 0; kc < 2; ++kc)
                bf[nt][kc] = *(const h8*)&sh.c.Wt1[nt * 16 + m16][kc * 32 + quad * 8];
#pragma unroll
        for (int mt = 0; mt < 4; ++mt) {
            int m0 = wave * 64 + mt * 16;
            h8 a0 = *(const h8*)&sh.c.A0[m0 + m16][quad * 8];
            h8 a1 = *(const h8*)&sh.c.A0[m0 + m16][32 + quad * 8];
#pragma unroll
            for (int nt = 0; nt < 4; ++nt) {
                f4v acc = {0.f, 0.f, 0.f, 0.f};
                acc = __builtin_amdgcn_mfma_f32_16x16x32_f16(a0, bf[nt][0], acc, 0, 0, 0);
                acc = __builtin_amdgcn_mfma_f32_16x16x32_f16(a1, bf[nt][1], acc, 0, 0, 0);
                int n = nt * 16 + m16;
                float bb = sh.c.bias[n];
#pragma unroll
                for (int r = 0; r < 4; ++r)
                    sh.c.A1[m0 + quad * 4 + r][n] =
                        (_Float16)fmaxf(acc[r] + bb, 0.0f);
            }
        }
    }
    __syncthreads();   // fence: A1 stores -> layer-2 A-fragment reads

    // --- layer 2: A1(h1) x Wt2 -> A0(h2), N=64, K=64 ---
    {
        h8 bf[4][2];
#pragma unroll
        for (int nt = 0; nt < 4; ++nt)
#pragma unroll
            for (int kc = 0; kc < 2; ++kc)
                bf[nt][kc] = *(const h8*)&sh.c.Wt2[nt * 16 + m16][kc * 32 + quad * 8];
#pragma unroll
        for (int mt = 0; mt < 4; ++mt) {
            int m0 = wave * 64 + mt * 16;
            h8 a0 = *(const h8*)&sh.c.A1[m0 + m16][quad * 8];
            h8 a1 = *(const h8*)&sh.c.A1[m0 + m16][32 + quad * 8];
#pragma unroll
            for (int nt = 0; nt < 4; ++nt) {
                f4v acc = {0.f, 0.f, 0.f, 0.f};
                acc = __builtin_amdgcn_mfma_f32_16x16x32_f16(a0, bf[nt][0], acc, 0, 0, 0);
                acc = __builtin_amdgcn_mfma_f32_16x16x32_f16(a1, bf[nt][1], acc, 0, 0, 0);
                int n = nt * 16 + m16;
                float bb = sh.c.bias[64 + n];
#pragma unroll
                for (int r = 0; r < 4; ++r)
                    sh.c.A0[m0 + quad * 4 + r][n] =
                        (_Float16)fmaxf(acc[r] + bb, 0.0f);
            }
        }
    }
    __syncthreads();   // fence: A0(h2) stores -> layer-3 A-fragment reads

    // --- layer 3: A0(h2) x Wt3, N=128, K=64; fused relu+bias+masked max ---
    {
        h8 bf[8][2];
#pragma unroll
        for (int nt = 0; nt < 8; ++nt)
#pragma unroll
            for (int kc = 0; kc < 2; ++kc)
                bf[nt][kc] = *(const h8*)&sh.c.Wt3[nt * 16 + m16][kc * 32 + quad * 8];
        float best[8];
#pragma unroll
        for (int nt = 0; nt < 8; ++nt) best[nt] = -INFINITY;
#pragma unroll
        for (int mt = 0; mt < 4; ++mt) {
            int m0 = wave * 64 + mt * 16;
            h8 a0 = *(const h8*)&sh.c.A0[m0 + m16][quad * 8];
            h8 a1 = *(const h8*)&sh.c.A0[m0 + m16][32 + quad * 8];
#pragma unroll
            for (int nt = 0; nt < 8; ++nt) {
                f4v acc = {0.f, 0.f, 0.f, 0.f};
                acc = __builtin_amdgcn_mfma_f32_16x16x32_f16(a0, bf[nt][0], acc, 0, 0, 0);
                acc = __builtin_amdgcn_mfma_f32_16x16x32_f16(a1, bf[nt][1], acc, 0, 0, 0);
                int n = nt * 16 + m16;
                float bb = sh.c.bias[128 + n];
#pragma unroll
                for (int r = 0; r < 4; ++r) {
                    int krow = mt * 16 + quad * 4 + r;   // row within centroid
                    float v = fmaxf(acc[r] + bb, 0.0f);
                    if (krow < cntw) best[nt] = fmaxf(best[nt], v);
                }
            }
        }
#pragma unroll
        for (int nt = 0; nt < 8; ++nt)
            sh.c.red[wave][quad][nt * 16 + m16] = best[nt];
    }
    __syncthreads();

    // --- final: max over 4 quads, write feat_out ---
    {
        int w2 = tid >> 6, n = tid & 63;
#pragma unroll
        for (int h = 0; h < 2; ++h) {
            int n2 = n + h * 64;
            float o = fmaxf(fmaxf(sh.c.red[w2][0][n2], sh.c.red[w2][1][n2]),
                            fmaxf(sh.c.red[w2][2][n2], sh.c.red[w2][3][n2]));
            feat_out[(size_t)(b * kM + cl0 + w2) * kO + n2] = o;
        }
    }
}

// ---------------------------------------------------------------------------
extern "C" void kernel_launch(void* const* d_in, const int* in_sizes, int n_in,
                              void* d_out, int out_size, void* d_ws, size_t ws_size,
                              hipStream_t stream) {
    const float* pos = (const float*)d_in[0];
    // d_in[1] = batch (unused; implied by layout)
    const float* x  = (const float*)d_in[2];
    const float* W1 = (const float*)d_in[3];
    const float* b1 = (const float*)d_in[4];
    const float* W2 = (const float*)d_in[5];
    const float* b2 = (const float*)d_in[6];
    const float* W3 = (const float*)d_in[7];
    const float* b3 = (const float*)d_in[8];

    float* out = (float*)d_out;
    float* cent_out  = out;                                   // [B*M, 3]
    float* feat_out  = out + (size_t)kB * kM * 3;             // [B*M, 128]
    float* batch_out = out + (size_t)kB * kM * (3 + kO);      // [B*M]

    char* ws = (char*)d_ws;
    int* prog           = (int*)ws;                           // 128 ints (strided)
    unsigned int* stage = (unsigned int*)(ws + 512);          // B*M*3 uints

    init_kernel<<<1, 128, 0, stream>>>(prog);
    mega_kernel<<<kB + (kB * kM) / 4, 256, 0, stream>>>(
        pos, x, W1, b1, W2, b2, W3, b3, stage, prog,
        cent_out, feat_out, batch_out);
}

// Round 8
// 2154.389 us; speedup vs baseline: 1.0008x; 1.0008x over previous
//
#include <hip/hip_runtime.h>
#include <stdint.h>
#include <math.h>

// Problem constants (from reference)
constexpr int kB = 8;      // clouds
constexpr int kP = 8192;   // points per cloud
constexpr int kF = 32;     // feature dim
constexpr int kM = 2048;   // centroids per cloud (P * 0.25)
constexpr int kK = 64;     // max neighbors
constexpr int kO = 128;    // output dim

typedef float v2f __attribute__((ext_vector_type(2)));
typedef _Float16 h8 __attribute__((ext_vector_type(8)));
typedef float f4v __attribute__((ext_vector_type(4)));
typedef unsigned long long u64x2 __attribute__((ext_vector_type(2)));

// Exact-f32 squared distance matching numpy: square elementwise, then
// sequential sum ((dx2+dy2)+dz2). contract(off) forbids fma fusion so this
// matches numpy bit-for-bit regardless of -ffp-contract=fast default.
__device__ __forceinline__ float dist2(float ax, float ay, float az,
                                       float bx, float by, float bz) {
#pragma clang fp contract(off)
    float dx = ax - bx, dy = ay - by, dz = az - bz;
    return (dx * dx + dy * dy) + dz * dz;
}

// One DPP step of a u64 (hi,lo) max-reduce. CTRL must be an immediate ->
// template parameter. bound_ctrl=true: invalid source lanes read 0, and
// (0,0) never wins because all real keys have klo = ~idx != 0.
// Compare as a single u64 '>' (lexicographic == the (hi>)||(hi==&&lo>)
// ladder). Plain C++ — no asm (r1/r5/r7 lesson: any inline asm in the FPS
// loop regresses; compiler's own interleave wins at every granularity).
template <int CTRL>
__device__ __forceinline__ void dpp_max_step(unsigned int& khi, unsigned int& klo) {
    unsigned int ohi = (unsigned int)__builtin_amdgcn_update_dpp(
        0, (int)khi, CTRL, 0xf, 0xf, true);
    unsigned int olo = (unsigned int)__builtin_amdgcn_update_dpp(
        0, (int)klo, CTRL, 0xf, 0xf, true);
    unsigned long long k = ((unsigned long long)khi << 32) | klo;
    unsigned long long o = ((unsigned long long)ohi << 32) | olo;
    bool take = o > k;
    khi = take ? ohi : khi;
    klo = take ? olo : klo;
}

// Zero the progress flags (d_ws is poisoned 0xAA before every launch).
__global__ void init_kernel(int* __restrict__ prog) {
    if (threadIdx.x < 128) prog[threadIdx.x] = 0;
}

// Role-union LDS. fps: big coord arrays (~100 KB). consumer: fp16 MFMA
// tiles + transposed fp16 weights (~121 KB). 1 block/CU either way.
union SharedU {
    struct {
        float sxp[kP], syp[kP], szp[kP];       // SoA cloud copy
        unsigned short widx[kM];               // winner index per iteration
        alignas(16) unsigned long long part[2][4];  // ping-pong wave partials
    } f;
    struct {
        _Float16 A0[256][72];                  // msg (cols 0..63), reused as h2
        _Float16 A1[256][72];                  // h1
        _Float16 Wt1[64][72];                  // W1^T [n][k], k>=35 zero
        _Float16 Wt2[64][72];                  // W2^T [n][k]
        _Float16 Wt3[128][72];                 // W3^T [n][k]
        float bias[256];                       // b1 | b2 | b3
        float red[4][4][128];                  // [centroid][quad][col]
        int   s_nb[4][kK];
        int   s_cnt[4];
    } c;
};

// ---------------------------------------------------------------------------
// Mega-kernel: producer/consumer overlap.
//  blocks 0..7    : FPS for cloud b (r6 structure + parallel-gather tail —
//                   the single change this round).
//  blocks 8..4103 : 4 consecutive centroids of cloud b = i&7.
//                   Stage weights -> spin on prog[b] -> per-wave ball query
//                   -> per-wave gather -> per-wave fp16 MFMA MLP (fp32 acc)
//                   -> fused masked max -> cross-quad reduce -> feat_out.
// NOTE: __syncthreads() at EVERY consumer phase boundary. Wave-internal DS
// ordering is a HW property, but the compiler may hoist LDS loads (s_cnt is
// loop-invariant and never stored by this thread) above prior phases'
// stores — that hoist caused r13's garbage-index global OOB fault. Barriers
// are full compiler+HW fences; cost ~100cyc each vs ~15µs block.
// ---------------------------------------------------------------------------
__global__ __launch_bounds__(256, 1) void mega_kernel(
    const float* __restrict__ pos, const float* __restrict__ x,
    const float* __restrict__ W1, const float* __restrict__ b1,
    const float* __restrict__ W2, const float* __restrict__ b2,
    const float* __restrict__ W3, const float* __restrict__ b3,
    unsigned int* __restrict__ stage, int* __restrict__ prog,
    float* __restrict__ cent_out, float* __restrict__ feat_out,
    float* __restrict__ batch_out) {
    __shared__ SharedU sh;

    const int tid = threadIdx.x;
    const int wave = tid >> 6, lane = tid & 63;

    if (blockIdx.x < (unsigned)kB) {
        // ======================= FPS role ==================================
        const int b = blockIdx.x;
        const float* pb = pos + (size_t)b * kP * 3;

        v2f px2[16], py2[16], pz2[16], dd2[16];
#pragma unroll
        for (int q = 0; q < 32; ++q) {
            int i = tid + q * 256;
            float X = pb[i * 3 + 0];
            float Y = pb[i * 3 + 1];
            float Z = pb[i * 3 + 2];
            sh.f.sxp[i] = X; sh.f.syp[i] = Y; sh.f.szp[i] = Z;
            if (q & 1) { px2[q >> 1].y = X; py2[q >> 1].y = Y; pz2[q >> 1].y = Z; }
            else       { px2[q >> 1].x = X; py2[q >> 1].x = Y; pz2[q >> 1].x = Z; }
        }
#pragma unroll
        for (int q = 0; q < 16; ++q) dd2[q] = (v2f){INFINITY, INFINITY};

        if (tid == 0) sh.f.widx[0] = 0;
        __syncthreads();

        float lx = sh.f.sxp[0], ly = sh.f.syp[0], lz = sh.f.szp[0];
        if (tid == 0) {
            size_t o = (size_t)(b * kM) * 3;
            __hip_atomic_store(&stage[o + 0], __float_as_uint(lx),
                               __ATOMIC_RELAXED, __HIP_MEMORY_SCOPE_AGENT);
            __hip_atomic_store(&stage[o + 1], __float_as_uint(ly),
                               __ATOMIC_RELAXED, __HIP_MEMORY_SCOPE_AGENT);
            __hip_atomic_store(&stage[o + 2], __float_as_uint(lz),
                               __ATOMIC_RELAXED, __HIP_MEMORY_SCOPE_AGENT);
            __hip_atomic_store(&prog[b * 16], 1,
                               __ATOMIC_RELEASE, __HIP_MEMORY_SCOPE_AGENT);
        }

        for (int m = 1; m < kM; ++m) {
            v2f lxv = {lx, lx}, lyv = {ly, ly}, lzv = {lz, lz};
#pragma unroll
            for (int q = 0; q < 16; ++q) {
#pragma clang fp contract(off)
                v2f dx = px2[q] - lxv;
                v2f dy = py2[q] - lyv;
                v2f dz = pz2[q] - lzv;
                v2f d2 = (dx * dx + dy * dy) + dz * dz;
                dd2[q].x = fminf(dd2[q].x, d2.x);
                dd2[q].y = fminf(dd2[q].y, d2.y);
            }

            // Fused argmax tree over 32 slots: at every node the left child
            // covers strictly lower slots; right wins only on STRICT '>'.
            // => max value with lowest slot on ties == reference first-max
            // (global point index i = tid + slot*256 is slot-major per thread).
            float v0[16]; int s0[16];
#pragma unroll
            for (int q = 0; q < 16; ++q) {
                bool t = dd2[q].y > dd2[q].x;
                v0[q] = t ? dd2[q].y : dd2[q].x;
                s0[q] = t ? (2 * q + 1) : (2 * q);
            }
            float v1[8]; int s1[8];
#pragma unroll
            for (int q = 0; q < 8; ++q) {
                bool t = v0[2 * q + 1] > v0[2 * q];
                v1[q] = t ? v0[2 * q + 1] : v0[2 * q];
                s1[q] = t ? s0[2 * q + 1] : s0[2 * q];
            }
            float v2[4]; int s2[4];
#pragma unroll
            for (int q = 0; q < 4; ++q) {
                bool t = v1[2 * q + 1] > v1[2 * q];
                v2[q] = t ? v1[2 * q + 1] : v1[2 * q];
                s2[q] = t ? s1[2 * q + 1] : s1[2 * q];
            }
            float v3[2]; int s3[2];
#pragma unroll
            for (int q = 0; q < 2; ++q) {
                bool t = v2[2 * q + 1] > v2[2 * q];
                v3[q] = t ? v2[2 * q + 1] : v2[2 * q];
                s3[q] = t ? s2[2 * q + 1] : s2[2 * q];
            }
            bool tf = v3[1] > v3[0];
            float bv = tf ? v3[1] : v3[0];
            int bq = tf ? s3[1] : s3[0];

            unsigned int bidx = (unsigned int)(tid + bq * 256);
            unsigned int khi = __float_as_uint(bv);
            unsigned int klo = (unsigned int)(~bidx);

            dpp_max_step<0x111>(khi, klo);
            dpp_max_step<0x112>(khi, klo);
            dpp_max_step<0x114>(khi, klo);
            dpp_max_step<0x118>(khi, klo);
            dpp_max_step<0x142>(khi, klo);
            dpp_max_step<0x143>(khi, klo);
            if (lane == 63)
                sh.f.part[m & 1][wave] = ((unsigned long long)khi << 32) | klo;
            __syncthreads();

            // Tail: read 4 wave partials (2 x b128), decode ALL 4 candidate
            // indices immediately and issue all 12 SoA broadcast gathers
            // (independent of the compares -> compiler schedules them in
            // parallel with the key-combine tree), then select coords by
            // cndmask. Scalar same-address LDS reads are true broadcasts
            // (conflict-free), unlike r2's float4 b128 variant. Keys are
            // unique (embed ~idx) -> strict max == reference winner.
            u64x2 pA = *(const u64x2*)&sh.f.part[m & 1][0];
            u64x2 pB = *(const u64x2*)&sh.f.part[m & 1][2];
            unsigned int cw0 = ~(unsigned int)pA.x, cw1 = ~(unsigned int)pA.y;
            unsigned int cw2 = ~(unsigned int)pB.x, cw3 = ~(unsigned int)pB.y;
            float x0 = sh.f.sxp[cw0], y0 = sh.f.syp[cw0], z0 = sh.f.szp[cw0];
            float x1 = sh.f.sxp[cw1], y1 = sh.f.syp[cw1], z1 = sh.f.szp[cw1];
            float x2 = sh.f.sxp[cw2], y2 = sh.f.syp[cw2], z2 = sh.f.szp[cw2];
            float x3 = sh.f.sxp[cw3], y3 = sh.f.syp[cw3], z3 = sh.f.szp[cw3];
            bool tA = pA.y > pA.x;
            unsigned long long ka = tA ? pA.y : pA.x;
            float xa = tA ? x1 : x0, ya = tA ? y1 : y0, za = tA ? z1 : z0;
            bool tB = pB.y > pB.x;
            unsigned long long kb = tB ? pB.y : pB.x;
            float xb = tB ? x3 : x2, yb = tB ? y3 : y2, zb = tB ? z3 : z2;
            bool tC = kb > ka;
            unsigned long long k = tC ? kb : ka;
            lx = tC ? xb : xa; ly = tC ? yb : ya; lz = tC ? zb : za;
            unsigned int wi = ~(unsigned int)k;
            if (tid == 0) sh.f.widx[m] = (unsigned short)wi;

            if ((m & 31) == 31) {
                int m0 = m - 31;
                if (tid < 96) {
                    int mm = m0 + tid / 3;
                    int comp = tid % 3;
                    unsigned int wv = (mm == m) ? wi
                                                : (unsigned int)sh.f.widx[mm];
                    float v = (comp == 0) ? sh.f.sxp[wv]
                            : (comp == 1) ? sh.f.syp[wv] : sh.f.szp[wv];
                    __hip_atomic_store(&stage[(size_t)(b * kM + mm) * 3 + comp],
                                       __float_as_uint(v),
                                       __ATOMIC_RELAXED, __HIP_MEMORY_SCOPE_AGENT);
                }
                __syncthreads();
                if (tid == 0)
                    __hip_atomic_store(&prog[b * 16], m + 1,
                                       __ATOMIC_RELEASE, __HIP_MEMORY_SCOPE_AGENT);
            }
        }
        __syncthreads();

#pragma unroll
        for (int q = 0; q < kM / 256; ++q) {
            int i = tid + q * 256;
            unsigned int wi = sh.f.widx[i];
            size_t o = (size_t)(b * kM + i) * 3;
            cent_out[o + 0] = sh.f.sxp[wi];
            cent_out[o + 1] = sh.f.syp[wi];
            cent_out[o + 2] = sh.f.szp[wi];
        }
        return;
    }

    // ======================= consumer role (G=4, MFMA) =====================
    const int i = (int)blockIdx.x - kB;
    const int b = i & 7;                 // cloud-rotated dispatch
    const int cl0 = (i >> 3) * 4;        // first of 4 centroids

    // --- stage weights/biases (independent of fps progress) ---
    for (int idx = tid; idx < 64 * 64; idx += 256) {
        int n = idx & 63, kk = idx >> 6;
        sh.c.Wt1[n][kk] = (_Float16)((kk < 35) ? W1[kk * 64 + n] : 0.0f);
        sh.c.Wt2[n][kk] = (_Float16)W2[kk * 64 + n];
    }
    for (int idx = tid; idx < 64 * 128; idx += 256) {
        int n = idx & 127, kk = idx >> 7;
        sh.c.Wt3[n][kk] = (_Float16)W3[kk * 128 + n];
    }
    sh.c.bias[tid] = (tid < 64) ? b1[tid] : (tid < 128) ? b2[tid - 64]
                                                        : b3[tid - 128];

    // --- wait until fps has published all 4 centroids ---
    if (tid == 0) {
        int p;
        while ((p = __hip_atomic_load(&prog[b * 16], __ATOMIC_ACQUIRE,
                                      __HIP_MEMORY_SCOPE_AGENT)) < cl0 + 4) {
            if (cl0 + 4 - p > 128) __builtin_amdgcn_s_sleep(64);
            else                   __builtin_amdgcn_s_sleep(8);
        }
    }
    __syncthreads();   // orders weight staging + spin vs everything below

    // --- ball query: wave w owns centroid cl0+w (fp32-exact) ---
    const int c = b * kM + cl0 + wave;
    float cx = __uint_as_float(__hip_atomic_load(&stage[(size_t)c * 3 + 0],
                   __ATOMIC_RELAXED, __HIP_MEMORY_SCOPE_AGENT));
    float cy = __uint_as_float(__hip_atomic_load(&stage[(size_t)c * 3 + 1],
                   __ATOMIC_RELAXED, __HIP_MEMORY_SCOPE_AGENT));
    float cz = __uint_as_float(__hip_atomic_load(&stage[(size_t)c * 3 + 2],
                   __ATOMIC_RELAXED, __HIP_MEMORY_SCOPE_AGENT));
    {
        const float R2 = (float)(0.2 * 0.2);
        const float* pb = pos + (size_t)b * kP * 3;
        int cnt = 0;
        for (int p0 = 0; p0 < kP && cnt < kK; p0 += 64) {
            int idx = p0 + lane;
            float X = pb[idx * 3 + 0], Y = pb[idx * 3 + 1], Z = pb[idx * 3 + 2];
            float d2 = dist2(X, Y, Z, cx, cy, cz);
            bool in = d2 <= R2;
            unsigned long long mask = __ballot(in);
            int rank = __popcll(mask & ((1ull << lane) - 1ull));
            if (in && cnt + rank < kK) sh.c.s_nb[wave][cnt + rank] = idx;
            cnt = min(cnt + (int)__popcll(mask), kK);
        }
        if (lane == 0) { sh.c.s_cnt[wave] = cnt; batch_out[c] = (float)b; }
    }
    __syncthreads();   // fence: s_nb/s_cnt stores -> reads (compiler+HW)
    const int cntw = sh.c.s_cnt[wave];

    // --- gather: thread = row tid = (wave,lane); msg cols 0..63 (35 used) ---
    {
        int k = lane;
        if (k < cntw) {
            int n = sh.c.s_nb[wave][k];
            const float4* xr4 = (const float4*)(x + ((size_t)b * kP + n) * kF);
#pragma unroll
            for (int t = 0; t < 4; ++t) {
                float4 a4 = xr4[2 * t], c4 = xr4[2 * t + 1];
                h8 o = {(_Float16)a4.x, (_Float16)a4.y, (_Float16)a4.z,
                        (_Float16)a4.w, (_Float16)c4.x, (_Float16)c4.y,
                        (_Float16)c4.z, (_Float16)c4.w};
                *(h8*)&sh.c.A0[tid][t * 8] = o;
            }
            float dx = pos[((size_t)b * kP + n) * 3 + 0] - cx;
            float dy = pos[((size_t)b * kP + n) * 3 + 1] - cy;
            float dz = pos[((size_t)b * kP + n) * 3 + 2] - cz;
            h8 o4 = {(_Float16)dx, (_Float16)dy, (_Float16)dz,
                     (_Float16)0.f, (_Float16)0.f, (_Float16)0.f,
                     (_Float16)0.f, (_Float16)0.f};
            *(h8*)&sh.c.A0[tid][32] = o4;
            h8 z = {};
            *(h8*)&sh.c.A0[tid][40] = z;
            *(h8*)&sh.c.A0[tid][48] = z;
            *(h8*)&sh.c.A0[tid][56] = z;
        } else {
            h8 z = {};
#pragma unroll
            for (int t = 0; t < 8; ++t) *(h8*)&sh.c.A0[tid][t * 8] = z;
        }
    }
    __syncthreads();   // fence: A0 stores -> MFMA A-fragment reads

    const int m16 = lane & 15, quad = lane >> 4;

    // --- layer 1: A0(msg) x Wt1 -> A1(h1), N=64, K=64 (fp16 MFMA, f32 acc)
    {
        h8 bf[4][2];
#pragma unroll
        for (int nt = 0; nt < 4; ++nt)
#pragma unroll
            for (int kc = 0; kc < 2; ++kc)
                bf[nt][kc] = *(const h8*)&sh.c.Wt1[nt * 16 + m16][kc * 32 + quad * 8];
#pragma unroll
        for (int mt = 0; mt < 4; ++mt) {
            int m0 = wave * 64 + mt * 16;
            h8 a0 = *(const h8*)&sh.c.A0[m0 + m16][quad * 8];
            h8 a1 = *(const h8*)&sh.c.A0[m0 + m16][32 + quad * 8];
#pragma unroll
            for (int nt = 0; nt < 4; ++nt) {
                f4v acc = {0.f, 0.f, 0.f, 0.f};
                acc = __builtin_amdgcn_mfma_f32_16x16x32_f16(a0, bf[nt][0], acc, 0, 0, 0);
                acc = __builtin_amdgcn_mfma_f32_16x16x32_f16(a1, bf[nt][1], acc, 0, 0, 0);
                int n = nt * 16 + m16;
                float bb = sh.c.bias[n];
#pragma unroll
                for (int r = 0; r < 4; ++r)
                    sh.c.A1[m0 + quad * 4 + r][n] =
                        (_Float16)fmaxf(acc[r] + bb, 0.0f);
            }
        }
    }
    __syncthreads();   // fence: A1 stores -> layer-2 A-fragment reads

    // --- layer 2: A1(h1) x Wt2 -> A0(h2), N=64, K=64 ---
    {
        h8 bf[4][2];
#pragma unroll
        for (int nt = 0; nt < 4; ++nt)
#pragma unroll
            for (int kc = 0; kc < 2; ++kc)
                bf[nt][kc] = *(const h8*)&sh.c.Wt2[nt * 16 + m16][kc * 32 + quad * 8];
#pragma unroll
        for (int mt = 0; mt < 4; ++mt) {
            int m0 = wave * 64 + mt * 16;
            h8 a0 = *(const h8*)&sh.c.A1[m0 + m16][quad * 8];
            h8 a1 = *(const h8*)&sh.c.A1[m0 + m16][32 + quad * 8];
#pragma unroll
            for (int nt = 0; nt < 4; ++nt) {
                f4v acc = {0.f, 0.f, 0.f, 0.f};
                acc = __builtin_amdgcn_mfma_f32_16x16x32_f16(a0, bf[nt][0], acc, 0, 0, 0);
                acc = __builtin_amdgcn_mfma_f32_16x16x32_f16(a1, bf[nt][1], acc, 0, 0, 0);
                int n = nt * 16 + m16;
                float bb = sh.c.bias[64 + n];
#pragma unroll
                for (int r = 0; r < 4; ++r)
                    sh.c.A0[m0 + quad * 4 + r][n] =
                        (_Float16)fmaxf(acc[r] + bb, 0.0f);
            }
        }
    }
    __syncthreads();   // fence: A0(h2) stores -> layer-3 A-fragment reads

    // --- layer 3: A0(h2) x Wt3, N=128, K=64; fused relu+bias+masked max ---
    {
        h8 bf[8][2];
#pragma unroll
        for (int nt = 0; nt < 8; ++nt)
#pragma unroll
            for (int kc = 0; kc < 2; ++kc)
                bf[nt][kc] = *(const h8*)&sh.c.Wt3[nt * 16 + m16][kc * 32 + quad * 8];
        float best[8];
#pragma unroll
        for (int nt = 0; nt < 8; ++nt) best[nt] = -INFINITY;
#pragma unroll
        for (int mt = 0; mt < 4; ++mt) {
            int m0 = wave * 64 + mt * 16;
            h8 a0 = *(const h8*)&sh.c.A0[m0 + m16][quad * 8];
            h8 a1 = *(const h8*)&sh.c.A0[m0 + m16][32 + quad * 8];
#pragma unroll
            for (int nt = 0; nt < 8; ++nt) {
                f4v acc = {0.f, 0.f, 0.f, 0.f};
                acc = __builtin_amdgcn_mfma_f32_16x16x32_f16(a0, bf[nt][0], acc, 0, 0, 0);
                acc = __builtin_amdgcn_mfma_f32_16x16x32_f16(a1, bf[nt][1], acc, 0, 0, 0);
                int n = nt * 16 + m16;
                float bb = sh.c.bias[128 + n];
#pragma unroll
                for (int r = 0; r < 4; ++r) {
                    int krow = mt * 16 + quad * 4 + r;   // row within centroid
                    float v = fmaxf(acc[r] + bb, 0.0f);
                    if (krow < cntw) best[nt] = fmaxf(best[nt], v);
                }
            }
        }
#pragma unroll
        for (int nt = 0; nt < 8; ++nt)
            sh.c.red[wave][quad][nt * 16 + m16] = best[nt];
    }
    __syncthreads();

    // --- final: max over 4 quads, write feat_out ---
    {
        int w2 = tid >> 6, n = tid & 63;
#pragma unroll
        for (int h = 0; h < 2; ++h) {
            int n2 = n + h * 64;
            float o = fmaxf(fmaxf(sh.c.red[w2][0][n2], sh.c.red[w2][1][n2]),
                            fmaxf(sh.c.red[w2][2][n2], sh.c.red[w2][3][n2]));
            feat_out[(size_t)(b * kM + cl0 + w2) * kO + n2] = o;
        }
    }
}

// ---------------------------------------------------------------------------
extern "C" void kernel_launch(void* const* d_in, const int* in_sizes, int n_in,
                              void* d_out, int out_size, void* d_ws, size_t ws_size,
                              hipStream_t stream) {
    const float* pos = (const float*)d_in[0];
    // d_in[1] = batch (unused; implied by layout)
    const float* x  = (const float*)d_in[2];
    const float* W1 = (const float*)d_in[3];
    const float* b1 = (const float*)d_in[4];
    const float* W2 = (const float*)d_in[5];
    const float* b2 = (const float*)d_in[6];
    const float* W3 = (const float*)d_in[7];
    const float* b3 = (const float*)d_in[8];

    float* out = (float*)d_out;
    float* cent_out  = out;                                   // [B*M, 3]
    float* feat_out  = out + (size_t)kB * kM * 3;             // [B*M, 128]
    float* batch_out = out + (size_t)kB * kM * (3 + kO);      // [B*M]

    char* ws = (char*)d_ws;
    int* prog           = (int*)ws;                           // 128 ints (strided)
    unsigned int* stage = (unsigned int*)(ws + 512);          // B*M*3 uints

    init_kernel<<<1, 128, 0, stream>>>(prog);
    mega_kernel<<<kB + (kB * kM) / 4, 256, 0, stream>>>(
        pos, x, W1, b1, W2, b2, W3, b3, stage, prog,
        cent_out, feat_out, batch_out);
}

// Round 9
// 2020.114 us; speedup vs baseline: 1.0673x; 1.0665x over previous
//
#include <hip/hip_runtime.h>
#include <stdint.h>
#include <math.h>

// Problem constants (from reference)
constexpr int kB = 8;      // clouds
constexpr int kP = 8192;   // points per cloud
constexpr int kF = 32;     // feature dim
constexpr int kM = 2048;   // centroids per cloud (P * 0.25)
constexpr int kK = 64;     // max neighbors
constexpr int kO = 128;    // output dim

typedef float v2f __attribute__((ext_vector_type(2)));
typedef _Float16 h8 __attribute__((ext_vector_type(8)));
typedef float f4v __attribute__((ext_vector_type(4)));
typedef unsigned long long u64x2 __attribute__((ext_vector_type(2)));

// Exact-f32 squared distance matching numpy: square elementwise, then
// sequential sum ((dx2+dy2)+dz2). contract(off) forbids fma fusion so this
// matches numpy bit-for-bit regardless of -ffp-contract=fast default.
__device__ __forceinline__ float dist2(float ax, float ay, float az,
                                       float bx, float by, float bz) {
#pragma clang fp contract(off)
    float dx = ax - bx, dy = ay - by, dz = az - bz;
    return (dx * dx + dy * dy) + dz * dz;
}

// One DPP step of a u64 (hi,lo) max-reduce. CTRL must be an immediate ->
// template parameter. bound_ctrl=true: invalid source lanes read 0, and
// (0,0) never wins because all real keys have klo = ~idx != 0.
// Compare as a single u64 '>' (lexicographic == the (hi>)||(hi==&&lo>)
// ladder). Plain C++ — no asm (r1/r5/r7: any inline asm in the FPS loop
// regresses at every granularity; the compiler's interleave wins).
template <int CTRL>
__device__ __forceinline__ void dpp_max_step(unsigned int& khi, unsigned int& klo) {
    unsigned int ohi = (unsigned int)__builtin_amdgcn_update_dpp(
        0, (int)khi, CTRL, 0xf, 0xf, true);
    unsigned int olo = (unsigned int)__builtin_amdgcn_update_dpp(
        0, (int)klo, CTRL, 0xf, 0xf, true);
    unsigned long long k = ((unsigned long long)khi << 32) | klo;
    unsigned long long o = ((unsigned long long)ohi << 32) | olo;
    bool take = o > k;
    khi = take ? ohi : khi;
    klo = take ? olo : klo;
}

// Zero the progress flags (d_ws is poisoned 0xAA before every launch).
__global__ void init_kernel(int* __restrict__ prog) {
    if (threadIdx.x < 128) prog[threadIdx.x] = 0;
}

// Role-union LDS. fps: big coord arrays (~100 KB). consumer: fp16 MFMA
// tiles + transposed fp16 weights (~121 KB). 1 block/CU either way.
union SharedU {
    struct {
        float sxp[kP], syp[kP], szp[kP];       // SoA cloud copy
        unsigned short widx[kM];               // winner index per iteration
        alignas(16) unsigned long long part[2][4];  // ping-pong wave partials
    } f;
    struct {
        _Float16 A0[256][72];                  // msg (cols 0..63), reused as h2
        _Float16 A1[256][72];                  // h1
        _Float16 Wt1[64][72];                  // W1^T [n][k], k>=35 zero
        _Float16 Wt2[64][72];                  // W2^T [n][k]
        _Float16 Wt3[128][72];                 // W3^T [n][k]
        float bias[256];                       // b1 | b2 | b3
        float red[4][4][128];                  // [centroid][quad][col]
        int   s_nb[4][kK];
        int   s_cnt[4];
    } c;
};

// ---------------------------------------------------------------------------
// Mega-kernel: producer/consumer overlap. This is the r6 optimum (best
// measured: 1974 us). Phase ledger across the session:
//   update loop: pk-asm at 3 granularities -> all regress (+126..+400 us);
//   reduce/find: fused argmax tree (-23), u64 DPP cmp + b128 combine (-46);
//   tail: float4 gather (+30), parallel 12-gather (+116) -> already hidden;
//   structure: 2 waves/SIMD (+350) -> barrier-locked waves compete.
// Remaining time is the serial FPS chain's issue floor (~1000 cyc/iter)
// plus irreducible DPP/barrier/waitcnt latency — a structural floor for
// this design, not a counter roofline.
//  blocks 0..7    : FPS for cloud b (bit-exact vs reference).
//  blocks 8..4103 : 4 consecutive centroids of cloud b = i&7.
//                   Stage weights -> spin on prog[b] -> per-wave ball query
//                   -> per-wave gather -> per-wave fp16 MFMA MLP (fp32 acc)
//                   -> fused masked max -> cross-quad reduce -> feat_out.
// NOTE: __syncthreads() at EVERY consumer phase boundary. Wave-internal DS
// ordering is a HW property, but the compiler may hoist LDS loads (s_cnt is
// loop-invariant and never stored by this thread) above prior phases'
// stores — that hoist caused r13's garbage-index global OOB fault. Barriers
// are full compiler+HW fences; cost ~100cyc each vs ~15µs block.
// ---------------------------------------------------------------------------
__global__ __launch_bounds__(256, 1) void mega_kernel(
    const float* __restrict__ pos, const float* __restrict__ x,
    const float* __restrict__ W1, const float* __restrict__ b1,
    const float* __restrict__ W2, const float* __restrict__ b2,
    const float* __restrict__ W3, const float* __restrict__ b3,
    unsigned int* __restrict__ stage, int* __restrict__ prog,
    float* __restrict__ cent_out, float* __restrict__ feat_out,
    float* __restrict__ batch_out) {
    __shared__ SharedU sh;

    const int tid = threadIdx.x;
    const int wave = tid >> 6, lane = tid & 63;

    if (blockIdx.x < (unsigned)kB) {
        // ======================= FPS role ==================================
        const int b = blockIdx.x;
        const float* pb = pos + (size_t)b * kP * 3;

        v2f px2[16], py2[16], pz2[16], dd2[16];
#pragma unroll
        for (int q = 0; q < 32; ++q) {
            int i = tid + q * 256;
            float X = pb[i * 3 + 0];
            float Y = pb[i * 3 + 1];
            float Z = pb[i * 3 + 2];
            sh.f.sxp[i] = X; sh.f.syp[i] = Y; sh.f.szp[i] = Z;
            if (q & 1) { px2[q >> 1].y = X; py2[q >> 1].y = Y; pz2[q >> 1].y = Z; }
            else       { px2[q >> 1].x = X; py2[q >> 1].x = Y; pz2[q >> 1].x = Z; }
        }
#pragma unroll
        for (int q = 0; q < 16; ++q) dd2[q] = (v2f){INFINITY, INFINITY};

        if (tid == 0) sh.f.widx[0] = 0;
        __syncthreads();

        float lx = sh.f.sxp[0], ly = sh.f.syp[0], lz = sh.f.szp[0];
        if (tid == 0) {
            size_t o = (size_t)(b * kM) * 3;
            __hip_atomic_store(&stage[o + 0], __float_as_uint(lx),
                               __ATOMIC_RELAXED, __HIP_MEMORY_SCOPE_AGENT);
            __hip_atomic_store(&stage[o + 1], __float_as_uint(ly),
                               __ATOMIC_RELAXED, __HIP_MEMORY_SCOPE_AGENT);
            __hip_atomic_store(&stage[o + 2], __float_as_uint(lz),
                               __ATOMIC_RELAXED, __HIP_MEMORY_SCOPE_AGENT);
            __hip_atomic_store(&prog[b * 16], 1,
                               __ATOMIC_RELEASE, __HIP_MEMORY_SCOPE_AGENT);
        }

        for (int m = 1; m < kM; ++m) {
            v2f lxv = {lx, lx}, lyv = {ly, ly}, lzv = {lz, lz};
#pragma unroll
            for (int q = 0; q < 16; ++q) {
#pragma clang fp contract(off)
                v2f dx = px2[q] - lxv;
                v2f dy = py2[q] - lyv;
                v2f dz = pz2[q] - lzv;
                v2f d2 = (dx * dx + dy * dy) + dz * dz;
                dd2[q].x = fminf(dd2[q].x, d2.x);
                dd2[q].y = fminf(dd2[q].y, d2.y);
            }

            // Fused argmax tree over 32 slots: at every node the left child
            // covers strictly lower slots; right wins only on STRICT '>'.
            // => max value with lowest slot on ties == reference first-max
            // (global point index i = tid + slot*256 is slot-major per thread).
            float v0[16]; int s0[16];
#pragma unroll
            for (int q = 0; q < 16; ++q) {
                bool t = dd2[q].y > dd2[q].x;
                v0[q] = t ? dd2[q].y : dd2[q].x;
                s0[q] = t ? (2 * q + 1) : (2 * q);
            }
            float v1[8]; int s1[8];
#pragma unroll
            for (int q = 0; q < 8; ++q) {
                bool t = v0[2 * q + 1] > v0[2 * q];
                v1[q] = t ? v0[2 * q + 1] : v0[2 * q];
                s1[q] = t ? s0[2 * q + 1] : s0[2 * q];
            }
            float v2[4]; int s2[4];
#pragma unroll
            for (int q = 0; q < 4; ++q) {
                bool t = v1[2 * q + 1] > v1[2 * q];
                v2[q] = t ? v1[2 * q + 1] : v1[2 * q];
                s2[q] = t ? s1[2 * q + 1] : s1[2 * q];
            }
            float v3[2]; int s3[2];
#pragma unroll
            for (int q = 0; q < 2; ++q) {
                bool t = v2[2 * q + 1] > v2[2 * q];
                v3[q] = t ? v2[2 * q + 1] : v2[2 * q];
                s3[q] = t ? s2[2 * q + 1] : s2[2 * q];
            }
            bool tf = v3[1] > v3[0];
            float bv = tf ? v3[1] : v3[0];
            int bq = tf ? s3[1] : s3[0];

            unsigned int bidx = (unsigned int)(tid + bq * 256);
            unsigned int khi = __float_as_uint(bv);
            unsigned int klo = (unsigned int)(~bidx);

            dpp_max_step<0x111>(khi, klo);
            dpp_max_step<0x112>(khi, klo);
            dpp_max_step<0x114>(khi, klo);
            dpp_max_step<0x118>(khi, klo);
            dpp_max_step<0x142>(khi, klo);
            dpp_max_step<0x143>(khi, klo);
            if (lane == 63)
                sh.f.part[m & 1][wave] = ((unsigned long long)khi << 32) | klo;
            __syncthreads();

            // Pairwise combine of 4 wave partials (b128 loads, depth-2 tree).
            // Max is order-independent and keys unique -> same winner as the
            // serial scan.
            u64x2 pA = *(const u64x2*)&sh.f.part[m & 1][0];
            u64x2 pB = *(const u64x2*)&sh.f.part[m & 1][2];
            unsigned long long ka = pA.x > pA.y ? pA.x : pA.y;
            unsigned long long kb = pB.x > pB.y ? pB.x : pB.y;
            unsigned long long k  = ka > kb ? ka : kb;
            unsigned int wi = ~(unsigned int)k;
            lx = sh.f.sxp[wi]; ly = sh.f.syp[wi]; lz = sh.f.szp[wi];
            if (tid == 0) sh.f.widx[m] = (unsigned short)wi;

            if ((m & 31) == 31) {
                int m0 = m - 31;
                if (tid < 96) {
                    int mm = m0 + tid / 3;
                    int comp = tid % 3;
                    unsigned int w2 = (mm == m) ? wi
                                                : (unsigned int)sh.f.widx[mm];
                    float v = (comp == 0) ? sh.f.sxp[w2]
                            : (comp == 1) ? sh.f.syp[w2] : sh.f.szp[w2];
                    __hip_atomic_store(&stage[(size_t)(b * kM + mm) * 3 + comp],
                                       __float_as_uint(v),
                                       __ATOMIC_RELAXED, __HIP_MEMORY_SCOPE_AGENT);
                }
                __syncthreads();
                if (tid == 0)
                    __hip_atomic_store(&prog[b * 16], m + 1,
                                       __ATOMIC_RELEASE, __HIP_MEMORY_SCOPE_AGENT);
            }
        }
        __syncthreads();

#pragma unroll
        for (int q = 0; q < kM / 256; ++q) {
            int i = tid + q * 256;
            unsigned int wi = sh.f.widx[i];
            size_t o = (size_t)(b * kM + i) * 3;
            cent_out[o + 0] = sh.f.sxp[wi];
            cent_out[o + 1] = sh.f.syp[wi];
            cent_out[o + 2] = sh.f.szp[wi];
        }
        return;
    }

    // ======================= consumer role (G=4, MFMA) =====================
    const int i = (int)blockIdx.x - kB;
    const int b = i & 7;                 // cloud-rotated dispatch
    const int cl0 = (i >> 3) * 4;        // first of 4 centroids

    // --- stage weights/biases (independent of fps progress) ---
    for (int idx = tid; idx < 64 * 64; idx += 256) {
        int n = idx & 63, kk = idx >> 6;
        sh.c.Wt1[n][kk] = (_Float16)((kk < 35) ? W1[kk * 64 + n] : 0.0f);
        sh.c.Wt2[n][kk] = (_Float16)W2[kk * 64 + n];
    }
    for (int idx = tid; idx < 64 * 128; idx += 256) {
        int n = idx & 127, kk = idx >> 7;
        sh.c.Wt3[n][kk] = (_Float16)W3[kk * 128 + n];
    }
    sh.c.bias[tid] = (tid < 64) ? b1[tid] : (tid < 128) ? b2[tid - 64]
                                                        : b3[tid - 128];

    // --- wait until fps has published all 4 centroids ---
    if (tid == 0) {
        int p;
        while ((p = __hip_atomic_load(&prog[b * 16], __ATOMIC_ACQUIRE,
                                      __HIP_MEMORY_SCOPE_AGENT)) < cl0 + 4) {
            if (cl0 + 4 - p > 128) __builtin_amdgcn_s_sleep(64);
            else                   __builtin_amdgcn_s_sleep(8);
        }
    }
    __syncthreads();   // orders weight staging + spin vs everything below

    // --- ball query: wave w owns centroid cl0+w (fp32-exact) ---
    const int c = b * kM + cl0 + wave;
    float cx = __uint_as_float(__hip_atomic_load(&stage[(size_t)c * 3 + 0],
                   __ATOMIC_RELAXED, __HIP_MEMORY_SCOPE_AGENT));
    float cy = __uint_as_float(__hip_atomic_load(&stage[(size_t)c * 3 + 1],
                   __ATOMIC_RELAXED, __HIP_MEMORY_SCOPE_AGENT));
    float cz = __uint_as_float(__hip_atomic_load(&stage[(size_t)c * 3 + 2],
                   __ATOMIC_RELAXED, __HIP_MEMORY_SCOPE_AGENT));
    {
        const float R2 = (float)(0.2 * 0.2);
        const float* pb = pos + (size_t)b * kP * 3;
        int cnt = 0;
        for (int p0 = 0; p0 < kP && cnt < kK; p0 += 64) {
            int idx = p0 + lane;
            float X = pb[idx * 3 + 0], Y = pb[idx * 3 + 1], Z = pb[idx * 3 + 2];
            float d2 = dist2(X, Y, Z, cx, cy, cz);
            bool in = d2 <= R2;
            unsigned long long mask = __ballot(in);
            int rank = __popcll(mask & ((1ull << lane) - 1ull));
            if (in && cnt + rank < kK) sh.c.s_nb[wave][cnt + rank] = idx;
            cnt = min(cnt + (int)__popcll(mask), kK);
        }
        if (lane == 0) { sh.c.s_cnt[wave] = cnt; batch_out[c] = (float)b; }
    }
    __syncthreads();   // fence: s_nb/s_cnt stores -> reads (compiler+HW)
    const int cntw = sh.c.s_cnt[wave];

    // --- gather: thread = row tid = (wave,lane); msg cols 0..63 (35 used) ---
    {
        int k = lane;
        if (k < cntw) {
            int n = sh.c.s_nb[wave][k];
            const float4* xr4 = (const float4*)(x + ((size_t)b * kP + n) * kF);
#pragma unroll
            for (int t = 0; t < 4; ++t) {
                float4 a4 = xr4[2 * t], c4 = xr4[2 * t + 1];
                h8 o = {(_Float16)a4.x, (_Float16)a4.y, (_Float16)a4.z,
                        (_Float16)a4.w, (_Float16)c4.x, (_Float16)c4.y,
                        (_Float16)c4.z, (_Float16)c4.w};
                *(h8*)&sh.c.A0[tid][t * 8] = o;
            }
            float dx = pos[((size_t)b * kP + n) * 3 + 0] - cx;
            float dy = pos[((size_t)b * kP + n) * 3 + 1] - cy;
            float dz = pos[((size_t)b * kP + n) * 3 + 2] - cz;
            h8 o4 = {(_Float16)dx, (_Float16)dy, (_Float16)dz,
                     (_Float16)0.f, (_Float16)0.f, (_Float16)0.f,
                     (_Float16)0.f, (_Float16)0.f};
            *(h8*)&sh.c.A0[tid][32] = o4;
            h8 z = {};
            *(h8*)&sh.c.A0[tid][40] = z;
            *(h8*)&sh.c.A0[tid][48] = z;
            *(h8*)&sh.c.A0[tid][56] = z;
        } else {
            h8 z = {};
#pragma unroll
            for (int t = 0; t < 8; ++t) *(h8*)&sh.c.A0[tid][t * 8] = z;
        }
    }
    __syncthreads();   // fence: A0 stores -> MFMA A-fragment reads

    const int m16 = lane & 15, quad = lane >> 4;

    // --- layer 1: A0(msg) x Wt1 -> A1(h1), N=64, K=64 (fp16 MFMA, f32 acc)
    {
        h8 bf[4][2];
#pragma unroll
        for (int nt = 0; nt < 4; ++nt)
#pragma unroll
            for (int kc = 0; kc < 2; ++kc)
                bf[nt][kc] = *(const h8*)&sh.c.Wt1[nt * 16 + m16][kc * 32 + quad * 8];
#pragma unroll
        for (int mt = 0; mt < 4; ++mt) {
            int m0 = wave * 64 + mt * 16;
            h8 a0 = *(const h8*)&sh.c.A0[m0 + m16][quad * 8];
            h8 a1 = *(const h8*)&sh.c.A0[m0 + m16][32 + quad * 8];
#pragma unroll
            for (int nt = 0; nt < 4; ++nt) {
                f4v acc = {0.f, 0.f, 0.f, 0.f};
                acc = __builtin_amdgcn_mfma_f32_16x16x32_f16(a0, bf[nt][0], acc, 0, 0, 0);
                acc = __builtin_amdgcn_mfma_f32_16x16x32_f16(a1, bf[nt][1], acc, 0, 0, 0);
                int n = nt * 16 + m16;
                float bb = sh.c.bias[n];
#pragma unroll
                for (int r = 0; r < 4; ++r)
                    sh.c.A1[m0 + quad * 4 + r][n] =
                        (_Float16)fmaxf(acc[r] + bb, 0.0f);
            }
        }
    }
    __syncthreads();   // fence: A1 stores -> layer-2 A-fragment reads

    // --- layer 2: A1(h1) x Wt2 -> A0(h2), N=64, K=64 ---
    {
        h8 bf[4][2];
#pragma unroll
        for (int nt = 0; nt < 4; ++nt)
#pragma unroll
            for (int kc = 0; kc < 2; ++kc)
                bf[nt][kc] = *(const h8*)&sh.c.Wt2[nt * 16 + m16][kc * 32 + quad * 8];
#pragma unroll
        for (int mt = 0; mt < 4; ++mt) {
            int m0 = wave * 64 + mt * 16;
            h8 a0 = *(const h8*)&sh.c.A1[m0 + m16][quad * 8];
            h8 a1 = *(const h8*)&sh.c.A1[m0 + m16][32 + quad * 8];
#pragma unroll
            for (int nt = 0; nt < 4; ++nt) {
                f4v acc = {0.f, 0.f, 0.f, 0.f};
                acc = __builtin_amdgcn_mfma_f32_16x16x32_f16(a0, bf[nt][0], acc, 0, 0, 0);
                acc = __builtin_amdgcn_mfma_f32_16x16x32_f16(a1, bf[nt][1], acc, 0, 0, 0);
                int n = nt * 16 + m16;
                float bb = sh.c.bias[64 + n];
#pragma unroll
                for (int r = 0; r < 4; ++r)
                    sh.c.A0[m0 + quad * 4 + r][n] =
                        (_Float16)fmaxf(acc[r] + bb, 0.0f);
            }
        }
    }
    __syncthreads();   // fence: A0(h2) stores -> layer-3 A-fragment reads

    // --- layer 3: A0(h2) x Wt3, N=128, K=64; fused relu+bias+masked max ---
    {
        h8 bf[8][2];
#pragma unroll
        for (int nt = 0; nt < 8; ++nt)
#pragma unroll
            for (int kc = 0; kc < 2; ++kc)
                bf[nt][kc] = *(const h8*)&sh.c.Wt3[nt * 16 + m16][kc * 32 + quad * 8];
        float best[8];
#pragma unroll
        for (int nt = 0; nt < 8; ++nt) best[nt] = -INFINITY;
#pragma unroll
        for (int mt = 0; mt < 4; ++mt) {
            int m0 = wave * 64 + mt * 16;
            h8 a0 = *(const h8*)&sh.c.A0[m0 + m16][quad * 8];
            h8 a1 = *(const h8*)&sh.c.A0[m0 + m16][32 + quad * 8];
#pragma unroll
            for (int nt = 0; nt < 8; ++nt) {
                f4v acc = {0.f, 0.f, 0.f, 0.f};
                acc = __builtin_amdgcn_mfma_f32_16x16x32_f16(a0, bf[nt][0], acc, 0, 0, 0);
                acc = __builtin_amdgcn_mfma_f32_16x16x32_f16(a1, bf[nt][1], acc, 0, 0, 0);
                int n = nt * 16 + m16;
                float bb = sh.c.bias[128 + n];
#pragma unroll
                for (int r = 0; r < 4; ++r) {
                    int krow = mt * 16 + quad * 4 + r;   // row within centroid
                    float v = fmaxf(acc[r] + bb, 0.0f);
                    if (krow < cntw) best[nt] = fmaxf(best[nt], v);
                }
            }
        }
#pragma unroll
        for (int nt = 0; nt < 8; ++nt)
            sh.c.red[wave][quad][nt * 16 + m16] = best[nt];
    }
    __syncthreads();

    // --- final: max over 4 quads, write feat_out ---
    {
        int w2 = tid >> 6, n = tid & 63;
#pragma unroll
        for (int h = 0; h < 2; ++h) {
            int n2 = n + h * 64;
            float o = fmaxf(fmaxf(sh.c.red[w2][0][n2], sh.c.red[w2][1][n2]),
                            fmaxf(sh.c.red[w2][2][n2], sh.c.red[w2][3][n2]));
            feat_out[(size_t)(b * kM + cl0 + w2) * kO + n2] = o;
        }
    }
}

// ---------------------------------------------------------------------------
extern "C" void kernel_launch(void* const* d_in, const int* in_sizes, int n_in,
                              void* d_out, int out_size, void* d_ws, size_t ws_size,
                              hipStream_t stream) {
    const float* pos = (const float*)d_in[0];
    // d_in[1] = batch (unused; implied by layout)
    const float* x  = (const float*)d_in[2];
    const float* W1 = (const float*)d_in[3];
    const float* b1 = (const float*)d_in[4];
    const float* W2 = (const float*)d_in[5];
    const float* b2 = (const float*)d_in[6];
    const float* W3 = (const float*)d_in[7];
    const float* b3 = (const float*)d_in[8];

    float* out = (float*)d_out;
    float* cent_out  = out;                                   // [B*M, 3]
    float* feat_out  = out + (size_t)kB * kM * 3;             // [B*M, 128]
    float* batch_out = out + (size_t)kB * kM * (3 + kO);      // [B*M]

    char* ws = (char*)d_ws;
    int* prog           = (int*)ws;                           // 128 ints (strided)
    unsigned int* stage = (unsigned int*)(ws + 512);          // B*M*3 uints

    init_kernel<<<1, 128, 0, stream>>>(prog);
    mega_kernel<<<kB + (kB * kM) / 4, 256, 0, stream>>>(
        pos, x, W1, b1, W2, b2, W3, b3, stage, prog,
        cent_out, feat_out, batch_out);
}